// Round 1
// baseline (549.982 us; speedup 1.0000x reference)
//
#include <hip/hip_runtime.h>

typedef __attribute__((ext_vector_type(8))) short short8;
typedef __attribute__((ext_vector_type(4))) float f32x4;

// Problem constants
// B=64 H=W=56 C=192 WS=7 SHIFT=3 NH=6 HD=32 NWH=NWW=8 NW=64 L=49
// BW = B*NW = 4096 windows; BH = BW*NH = 24576 window-heads

static constexpr size_t OFF_QKVWT = 0;                        // 576*192*2   = 221184
static constexpr size_t OFF_PWT   = 221184;                   // 192*192*2   =  73728
static constexpr size_t OFF_CMB   = 294912;                   // 4*6*49*49*4 = 230496
static constexpr size_t OFF_Q     = 525568;                   // 24576*49*32*2 = 77070336
static constexpr size_t OFF_K     = OFF_Q  + 77070336ull;
static constexpr size_t OFF_VT    = OFF_K  + 77070336ull;     // 24576*32*64*2 = 100663296
static constexpr size_t OFF_XO    = OFF_VT + 100663296ull;    // 4096*49*192*2 = 77070336
static constexpr size_t WS_NEED   = OFF_XO + 77070336ull;     // ~332.4 MB

__device__ __forceinline__ ushort f2bf(float f){
  uint x = __float_as_uint(f);
  x += 0x7fffu + ((x >> 16) & 1u);
  return (ushort)(x >> 16);
}

// ---------------------------------------------------------------- setup ----
// qkvwt[n][k] = bf16(qkv_w[k][n]); pwt[n][k] = bf16(proj_w[k][n]);
// cmb[c][h][i][j] = rel_bias + shift_mask for window-class c = (wh==7)*2+(ww==7)
__global__ void k_setup(const float* __restrict__ qkv_w, const float* __restrict__ proj_w,
                        const float* __restrict__ rel_table,
                        ushort* __restrict__ qkvwt, ushort* __restrict__ pwt,
                        float* __restrict__ cmb){
  int idx = blockIdx.x * 256 + threadIdx.x;
  if (idx < 576*192){
    int n = idx / 192, k = idx % 192;
    qkvwt[idx] = f2bf(qkv_w[k*576 + n]);
  } else if (idx < 576*192 + 192*192){
    int t = idx - 576*192;
    int n = t / 192, k = t % 192;
    pwt[t] = f2bf(proj_w[k*192 + n]);
  } else if (idx < 576*192 + 192*192 + 4*6*49*49){
    int t = idx - (576*192 + 192*192);
    int c  = t / (6*49*49);
    int r  = t % (6*49*49);
    int h  = r / (49*49);
    int ij = r % (49*49);
    int i = ij / 49, j = ij % 49;
    int ii = i/7, ic = i%7, ji = j/7, jc = j%7;
    int ridx = (ii - ji + 6)*13 + (ic - jc + 6);
    float b = rel_table[ridx*6 + h];
    int regi = ((c&2) ? (ii<4?1:2) : 0)*3 + ((c&1) ? (ic<4?1:2) : 0);
    int regj = ((c&2) ? (ji<4?1:2) : 0)*3 + ((c&1) ? (jc<4?1:2) : 0);
    cmb[t] = b + ((regi != regj) ? -100.0f : 0.0f);
  }
}

// ----------------------------------------------------------------- k_qkv ---
// One block per (batch,window). Gather rolled window -> LDS bf16 (swizzled),
// GEMM 64x576x192 with mfma 16x16x32. Stores q (scaled), k [49][32], vT [32][64].
__global__ __launch_bounds__(256) void k_qkv(const float* __restrict__ x,
                                             const ushort* __restrict__ qkvwt,
                                             const float* __restrict__ qkv_b,
                                             ushort* __restrict__ qw,
                                             ushort* __restrict__ kw,
                                             ushort* __restrict__ vtw){
  __shared__ ushort xa[64*192];          // rows padded to 64, XOR-swizzled
  const int bid = blockIdx.x;            // 0..4095
  const int b   = bid >> 6, win = bid & 63;
  const int wh  = win >> 3, ww  = win & 7;
  const int tid = threadIdx.x;

  // zero pad rows 49..63
  for (int t = tid; t < 15*48; t += 256){
    int l = 49 + t/48, c4 = t%48;
    *(ushort4*)((char*)xa + l*384 + c4*8) = make_ushort4(0,0,0,0);
  }
  // gather window rows (roll -3,-3), f32 -> bf16, swizzled LDS write
  for (int t = tid; t < 49*48; t += 256){
    int l = t/48, c4 = t%48;
    int i = l/7, j = l%7;
    int sh = wh*7 + i + 3; if (sh >= 56) sh -= 56;
    int sw = ww*7 + j + 3; if (sw >= 56) sw -= 56;
    float4 v = *(const float4*)(x + (((size_t)b*56 + sh)*56 + sw)*192 + c4*4);
    ushort4 u; u.x = f2bf(v.x); u.y = f2bf(v.y); u.z = f2bf(v.z); u.w = f2bf(v.w);
    *(ushort4*)((char*)xa + l*384 + ((c4*8) ^ ((l&7)<<4))) = u;
  }
  __syncthreads();

  const int wv = tid >> 6, lane = tid & 63;
  const int lj = lane & 15, lg = lane >> 4;
  const int n0 = wv * 144;               // each wave: 9 n-tiles of 16

  f32x4 acc[4][9];
  #pragma unroll
  for (int mt = 0; mt < 4; mt++)
    #pragma unroll
    for (int nt = 0; nt < 9; nt++) acc[mt][nt] = (f32x4){0.f,0.f,0.f,0.f};

  #pragma unroll
  for (int ks = 0; ks < 6; ks++){
    short8 a[4];
    #pragma unroll
    for (int mt = 0; mt < 4; mt++){
      int row = mt*16 + lj;
      a[mt] = *(const short8*)((const char*)xa + row*384 + (((ks*32 + lg*8)*2) ^ ((row&7)<<4)));
    }
    #pragma unroll
    for (int nt = 0; nt < 9; nt++){
      short8 bf = *(const short8*)(qkvwt + (size_t)(n0 + nt*16 + lj)*192 + ks*32 + lg*8);
      #pragma unroll
      for (int mt = 0; mt < 4; mt++)
        acc[mt][nt] = __builtin_amdgcn_mfma_f32_16x16x32_bf16(a[mt], bf, acc[mt][nt], 0, 0, 0);
    }
  }

  // epilogue: +bias, scale q, scatter to q / k / vT (bf16)
  #pragma unroll
  for (int nt = 0; nt < 9; nt++){
    int n = n0 + nt*16 + lj;
    int s = (n >= 384) ? 2 : ((n >= 192) ? 1 : 0);
    int r = n - s*192;
    int hh = r >> 5, d = r & 31;
    float bias = qkv_b[n];
    float scale = (s == 0) ? 0.17677669529663687f : 1.0f;
    size_t hb = (size_t)(bid*6 + hh);
    #pragma unroll
    for (int mt = 0; mt < 4; mt++){
      #pragma unroll
      for (int e = 0; e < 4; e++){
        int l = mt*16 + lg*4 + e;
        if (s == 2){
          // vT[d][l], pad l>=49 with 0 so PV B-frags never read stale NaNs
          ushort vv = (l < 49) ? f2bf(acc[mt][nt][e] + bias) : (ushort)0;
          vtw[(hb*32 + d)*64 + l] = vv;
        } else if (l < 49){
          ushort vv = f2bf((acc[mt][nt][e] + bias) * scale);
          if (s == 0) qw[(hb*49 + l)*32 + d] = vv;
          else        kw[(hb*49 + l)*32 + d] = vv;
        }
      }
    }
  }
}

// ---------------------------------------------------------------- k_attn ---
// One wave per (window, head): QK^T (16 mfma) + bias/mask + wave-parallel
// softmax + PV (16 mfma). P goes through XOR-swizzled LDS tile.
__global__ __launch_bounds__(64) void k_attn(const ushort* __restrict__ qw,
                                             const ushort* __restrict__ kw,
                                             const ushort* __restrict__ vtw,
                                             const float* __restrict__ cmb,
                                             ushort* __restrict__ xo){
  __shared__ ushort pl[64*64];
  const int bid  = blockIdx.x;           // 0..24575
  const int bwin = bid / 6, h = bid % 6;
  const int win  = bwin & 63;
  const int wh   = win >> 3, ww = win & 7;
  const int cc   = ((wh == 7) ? 2 : 0) + ((ww == 7) ? 1 : 0);
  const int lane = threadIdx.x;
  const int lj = lane & 15, lg = lane >> 4;
  const size_t base = (size_t)bid * 49 * 32;

  // QK^T
  short8 aq[4], bk[4];
  #pragma unroll
  for (int mt = 0; mt < 4; mt++){
    int row = mt*16 + lj; if (row > 48) row = 48;
    aq[mt] = *(const short8*)(qw + base + row*32 + lg*8);
  }
  #pragma unroll
  for (int nt = 0; nt < 4; nt++){
    int row = nt*16 + lj; if (row > 48) row = 48;
    bk[nt] = *(const short8*)(kw + base + row*32 + lg*8);
  }
  f32x4 sc[4][4];
  #pragma unroll
  for (int mt = 0; mt < 4; mt++)
    #pragma unroll
    for (int nt = 0; nt < 4; nt++)
      sc[mt][nt] = __builtin_amdgcn_mfma_f32_16x16x32_bf16(aq[mt], bk[nt], (f32x4){0.f,0.f,0.f,0.f}, 0, 0, 0);

  // bias + mask, row max
  const float* cb = cmb + ((size_t)cc*6 + h)*2401;
  float rmax[4][4];
  #pragma unroll
  for (int mt = 0; mt < 4; mt++){
    #pragma unroll
    for (int e = 0; e < 4; e++){
      int i = mt*16 + lg*4 + e; int ic = (i > 48) ? 48 : i;
      float m = -3.0e38f;
      #pragma unroll
      for (int nt = 0; nt < 4; nt++){
        int j = nt*16 + lj;
        float v = sc[mt][nt][e] + cb[ic*49 + ((j > 48) ? 48 : j)];
        if (j >= 49) v = -1.0e30f;
        sc[mt][nt][e] = v;
        m = fmaxf(m, v);
      }
      rmax[mt][e] = m;
    }
  }
  #pragma unroll
  for (int mt = 0; mt < 4; mt++)
    #pragma unroll
    for (int e = 0; e < 4; e++){
      float m = rmax[mt][e];
      m = fmaxf(m, __shfl_xor(m, 1, 16));
      m = fmaxf(m, __shfl_xor(m, 2, 16));
      m = fmaxf(m, __shfl_xor(m, 4, 16));
      m = fmaxf(m, __shfl_xor(m, 8, 16));
      rmax[mt][e] = m;
    }

  // p = exp(s-m): write bf16 into swizzled LDS; row sums
  float rsum[4][4];
  #pragma unroll
  for (int mt = 0; mt < 4; mt++){
    #pragma unroll
    for (int e = 0; e < 4; e++){
      int i = mt*16 + lg*4 + e;
      float s = 0.f;
      #pragma unroll
      for (int nt = 0; nt < 4; nt++){
        int j = nt*16 + lj;
        float p = __expf(sc[mt][nt][e] - rmax[mt][e]);
        s += p;
        *(ushort*)((char*)pl + i*128 + ((j*2) ^ ((i&7)<<4))) = f2bf(p);
      }
      s += __shfl_xor(s, 1, 16);
      s += __shfl_xor(s, 2, 16);
      s += __shfl_xor(s, 4, 16);
      s += __shfl_xor(s, 8, 16);
      rsum[mt][e] = s;
    }
  }
  __syncthreads();

  // PV: out[64][32] = P[64][64] @ V[64][32] (V read as vT[32][64])
  const size_t vbase = (size_t)bid * 32 * 64;
  short8 bv[2][2];
  #pragma unroll
  for (int dt = 0; dt < 2; dt++)
    #pragma unroll
    for (int ks = 0; ks < 2; ks++)
      bv[dt][ks] = *(const short8*)(vtw + vbase + (size_t)(dt*16 + lj)*64 + ks*32 + lg*8);

  f32x4 o[4][2];
  #pragma unroll
  for (int mt = 0; mt < 4; mt++){
    int row = mt*16 + lj;
    short8 ap0 = *(const short8*)((const char*)pl + row*128 + ((0*64 + lg*16) ^ ((row&7)<<4)));
    short8 ap1 = *(const short8*)((const char*)pl + row*128 + ((1*64 + lg*16) ^ ((row&7)<<4)));
    #pragma unroll
    for (int dt = 0; dt < 2; dt++){
      f32x4 t = __builtin_amdgcn_mfma_f32_16x16x32_bf16(ap0, bv[dt][0], (f32x4){0.f,0.f,0.f,0.f}, 0, 0, 0);
      o[mt][dt] = __builtin_amdgcn_mfma_f32_16x16x32_bf16(ap1, bv[dt][1], t, 0, 0, 0);
    }
  }

  // normalize + store xo bf16 (c = h*32 + d)
  const size_t xbase = (size_t)bwin * 49 * 192 + h*32;
  #pragma unroll
  for (int mt = 0; mt < 4; mt++){
    #pragma unroll
    for (int e = 0; e < 4; e++){
      int i = mt*16 + lg*4 + e;
      if (i < 49){
        float inv = 1.0f / rsum[mt][e];
        #pragma unroll
        for (int dt = 0; dt < 2; dt++)
          xo[xbase + (size_t)i*192 + dt*16 + lj] = f2bf(o[mt][dt][e] * inv);
      }
    }
  }
}

// ---------------------------------------------------------------- k_proj ---
// One block per window: out = xo @ proj_w + proj_b, scatter with roll(+3,+3).
__global__ __launch_bounds__(256) void k_proj(const ushort* __restrict__ xo,
                                              const ushort* __restrict__ pwt,
                                              const float* __restrict__ proj_b,
                                              float* __restrict__ out){
  __shared__ ushort xa[64*192];
  const int bid = blockIdx.x;
  const int b   = bid >> 6, win = bid & 63;
  const int wh  = win >> 3, ww  = win & 7;
  const int tid = threadIdx.x;

  for (int t = tid; t < 15*48; t += 256){
    int l = 49 + t/48, c4 = t%48;
    *(ushort4*)((char*)xa + l*384 + c4*8) = make_ushort4(0,0,0,0);
  }
  for (int t = tid; t < 49*48; t += 256){
    int l = t/48, c4 = t%48;
    ushort4 u = *(const ushort4*)(xo + ((size_t)bid*49 + l)*192 + c4*4);
    *(ushort4*)((char*)xa + l*384 + ((c4*8) ^ ((l&7)<<4))) = u;
  }
  __syncthreads();

  const int wv = tid >> 6, lane = tid & 63;
  const int lj = lane & 15, lg = lane >> 4;
  const int n0 = wv * 48;                 // each wave: 3 n-tiles of 16

  f32x4 acc[4][3];
  #pragma unroll
  for (int mt = 0; mt < 4; mt++)
    #pragma unroll
    for (int nt = 0; nt < 3; nt++) acc[mt][nt] = (f32x4){0.f,0.f,0.f,0.f};

  #pragma unroll
  for (int ks = 0; ks < 6; ks++){
    short8 a[4];
    #pragma unroll
    for (int mt = 0; mt < 4; mt++){
      int row = mt*16 + lj;
      a[mt] = *(const short8*)((const char*)xa + row*384 + (((ks*32 + lg*8)*2) ^ ((row&7)<<4)));
    }
    #pragma unroll
    for (int nt = 0; nt < 3; nt++){
      short8 bf = *(const short8*)(pwt + (size_t)(n0 + nt*16 + lj)*192 + ks*32 + lg*8);
      #pragma unroll
      for (int mt = 0; mt < 4; mt++)
        acc[mt][nt] = __builtin_amdgcn_mfma_f32_16x16x32_bf16(a[mt], bf, acc[mt][nt], 0, 0, 0);
    }
  }

  #pragma unroll
  for (int nt = 0; nt < 3; nt++){
    int n = n0 + nt*16 + lj;
    float pb = proj_b[n];
    #pragma unroll
    for (int mt = 0; mt < 4; mt++){
      #pragma unroll
      for (int e = 0; e < 4; e++){
        int l = mt*16 + lg*4 + e;
        if (l < 49){
          int i = l/7, j = l%7;
          int oh = wh*7 + i + 3; if (oh >= 56) oh -= 56;
          int ow = ww*7 + j + 3; if (ow >= 56) ow -= 56;
          out[(((size_t)b*56 + oh)*56 + ow)*192 + n] = acc[mt][nt][e] + pb;
        }
      }
    }
  }
}

// ------------------------------------------------------------------ launch -
extern "C" void kernel_launch(void* const* d_in, const int* in_sizes, int n_in,
                              void* d_out, int out_size, void* d_ws, size_t ws_size,
                              hipStream_t stream){
  const float* x         = (const float*)d_in[0];
  const float* qkv_w     = (const float*)d_in[1];
  const float* qkv_b     = (const float*)d_in[2];
  const float* proj_w    = (const float*)d_in[3];
  const float* proj_b    = (const float*)d_in[4];
  const float* rel_table = (const float*)d_in[5];

  if (ws_size < WS_NEED) return;   // would show as poison-level absmax -> ws too small

  char* ws = (char*)d_ws;
  ushort* qkvwt = (ushort*)(ws + OFF_QKVWT);
  ushort* pwt   = (ushort*)(ws + OFF_PWT);
  float*  cmb   = (float*) (ws + OFF_CMB);
  ushort* qw    = (ushort*)(ws + OFF_Q);
  ushort* kw    = (ushort*)(ws + OFF_K);
  ushort* vtw   = (ushort*)(ws + OFF_VT);
  ushort* xob   = (ushort*)(ws + OFF_XO);
  float* out = (float*)d_out;

  k_setup<<<dim3(802), dim3(256), 0, stream>>>(qkv_w, proj_w, rel_table, qkvwt, pwt, cmb);
  k_qkv  <<<dim3(4096), dim3(256), 0, stream>>>(x, qkvwt, qkv_b, qw, kw, vtw);
  k_attn <<<dim3(24576), dim3(64), 0, stream>>>(qw, kw, vtw, cmb, xob);
  k_proj <<<dim3(4096), dim3(256), 0, stream>>>(xob, pwt, proj_b, out);
}

// Round 3
// 318.674 us; speedup vs baseline: 1.7258x; 1.7258x over previous
//
#include <hip/hip_runtime.h>

typedef __attribute__((ext_vector_type(8))) short short8;
typedef __attribute__((ext_vector_type(4))) float f32x4;
typedef __attribute__((ext_vector_type(2))) unsigned int uint2v;
typedef __attribute__((ext_vector_type(4))) unsigned int uint4v;

// B=64 H=W=56 C=192 WS=7 SHIFT=3 NH=6 HD=32 NW=64 L=49; 4096 windows.
static constexpr size_t OFF_QKVWT = 0;                 // 576*192*2 = 221184
static constexpr size_t OFF_PWT   = 221184;            // 192*192*2 = 73728
static constexpr size_t OFF_QB    = 294912;            // 576*4     = 2304
static constexpr size_t OFF_CMB2  = 297216;            // 24*16*64*4 f32 = 393216 B
static constexpr size_t WS_NEED   = OFF_CMB2 + 393216;

__device__ __forceinline__ ushort f2bf(float f){
  uint x = __float_as_uint(f);
  x += 0x7fffu + ((x >> 16) & 1u);
  return (ushort)(x >> 16);
}
__device__ __forceinline__ uint pk2(float lo, float hi){
  return (uint)f2bf(lo) | ((uint)f2bf(hi) << 16);
}
// concat two 4-bf16 groups into one 8-bf16 mfma32 fragment (slots 0..3, 4..7)
__device__ __forceinline__ short8 cat(uint2v a, uint2v b){
  uint4v u; u[0] = a[0]; u[1] = a[1]; u[2] = b[0]; u[3] = b[1];
  return __builtin_bit_cast(short8, u);
}

// ---------------------------------------------------------------- setup ----
// qkvwt[n][k] = bf16(qkv_w[k][n]) with q-rows (n<192) pre-scaled by HD^-0.5.
// qb2 = qkv_b with q-part scaled. pwt[n][k] = bf16(proj_w[k][n]).
// cmb2[cc][h][jg][i][e] f32: bias+mask at (i, j=jg*4+e); -1e30 for j>=49 pad.
__global__ void k_setup(const float* __restrict__ qkv_w, const float* __restrict__ qkv_b,
                        const float* __restrict__ proj_w, const float* __restrict__ rel_table,
                        ushort* __restrict__ qkvwt, ushort* __restrict__ pwt,
                        float* __restrict__ qb2, float* __restrict__ cmb2){
  int idx = blockIdx.x * 256 + threadIdx.x;
  if (idx < 110592){
    int n = idx / 192, k = idx % 192;
    float v = qkv_w[k*576 + n];
    if (n < 192) v *= 0.17677669529663687f;
    qkvwt[idx] = f2bf(v);
  } else if (idx < 110592 + 36864){
    int t = idx - 110592;
    int n = t / 192, k = t % 192;
    pwt[t] = f2bf(proj_w[k*192 + n]);
  } else if (idx < 110592 + 36864 + 576){
    int n = idx - (110592 + 36864);
    qb2[n] = qkv_b[n] * (n < 192 ? 0.17677669529663687f : 1.0f);
  } else if (idx < 110592 + 36864 + 576 + 98304){
    int t = idx - (110592 + 36864 + 576);
    int cc = t / 24576, r = t % 24576;
    int h = r / 4096; r &= 4095;
    int jg = r >> 8, i = (r >> 2) & 63, e = r & 3;
    int j = jg*4 + e;
    float val;
    if (j >= 49) val = -1e30f;
    else if (i >= 49) val = 0.0f;
    else {
      int ii = i/7, ic = i%7, ji = j/7, jc = j%7;
      int ridx = (ii - ji + 6)*13 + (ic - jc + 6);
      float bsum = rel_table[ridx*6 + h];
      int regi = ((cc&2) ? (ii<4?1:2) : 0)*3 + ((cc&1) ? (ic<4?1:2) : 0);
      int regj = ((cc&2) ? (ji<4?1:2) : 0)*3 + ((cc&1) ? (jc<4?1:2) : 0);
      val = bsum + ((regi != regj) ? -100.0f : 0.0f);
    }
    cmb2[t] = val;
  }
}

// ---------------------------------------------------------------- fused ----
// One block per window, 6 waves = 6 heads. q/k/v/P never leave registers.
// All matrix ops use the session-verified mfma_f32_16x16x32_bf16 only; K=16
// sub-chains are built by concatenating two 4-elem e-groups into one 8-elem
// fragment on BOTH operands (slot-consistent => exact regardless of HW k map).
__global__ __launch_bounds__(384, 3) void k_fused(const float* __restrict__ x,
    const ushort* __restrict__ qkvwt, const float* __restrict__ qb2,
    const ushort* __restrict__ pwt, const float* __restrict__ proj_b,
    const f32x4* __restrict__ cmb2, float* __restrict__ out){
  __shared__ ushort xa[64*192];   // [l][c] bf16, XOR-swizzled, rows 49..63 = 0
  __shared__ ushort xo[64*200];   // [i][c] bf16, attn output for proj (pad 200)
  const int bid = blockIdx.x, b = bid >> 6, win = bid & 63;
  const int wh = win >> 3, ww = win & 7;
  const int cc = ((wh == 7) ? 2 : 0) + ((ww == 7) ? 1 : 0);
  const int tid = threadIdx.x;

  // ---- stage x window (roll -3,-3) -> xa bf16
  for (int t = tid; t < 15*48; t += 384){
    int l = 49 + t/48, c4 = t%48;
    *(ushort4*)((char*)xa + l*384 + ((c4*8) ^ ((l&7)<<4))) = make_ushort4(0,0,0,0);
  }
  for (int t = tid; t < 49*48; t += 384){
    int l = t/48, c4 = t%48;
    int i = l/7, j = l%7;
    int sh = wh*7 + i + 3; if (sh >= 56) sh -= 56;
    int sw = ww*7 + j + 3; if (sw >= 56) sw -= 56;
    float4 v = *(const float4*)(x + (((size_t)b*56 + sh)*56 + sw)*192 + c4*4);
    ushort4 u; u.x = f2bf(v.x); u.y = f2bf(v.y); u.z = f2bf(v.z); u.w = f2bf(v.w);
    *(ushort4*)((char*)xa + l*384 + ((c4*8) ^ ((l&7)<<4))) = u;
  }
  __syncthreads();

  const int h = tid >> 6, lane = tid & 63, lj = lane & 15, lg = lane >> 4;
  const int swz = (lj & 7) << 4;

  uint2v q16[2][4], k16[2][4], v16[2][4];  // [d-slice dt][l/j tile]; 4 bf16/lane

  { // ---- q,k via swapped GEMM: D[c_out][l], lane: col=l=lj, d in regs
    f32x4 acc[4][4];
    #pragma unroll
    for (int mt = 0; mt < 4; mt++)
      #pragma unroll
      for (int nt = 0; nt < 4; nt++) acc[mt][nt] = (f32x4){0.f,0.f,0.f,0.f};
    #pragma unroll
    for (int ks = 0; ks < 6; ks++){
      short8 xb[4];
      #pragma unroll
      for (int nt = 0; nt < 4; nt++)
        xb[nt] = *(const short8*)((const char*)xa + (nt*16+lj)*384 + ((ks*64 + lg*16) ^ swz));
      #pragma unroll
      for (int mt = 0; mt < 4; mt++){
        int row = (mt>>1)*192 + h*32 + (mt&1)*16 + lj;
        short8 wa = *(const short8*)(qkvwt + (size_t)row*192 + ks*32 + lg*8);
        #pragma unroll
        for (int nt = 0; nt < 4; nt++)
          acc[mt][nt] = __builtin_amdgcn_mfma_f32_16x16x32_bf16(wa, xb[nt], acc[mt][nt], 0, 0, 0);
      }
    }
    #pragma unroll
    for (int mt = 0; mt < 4; mt++){
      int cb = (mt>>1)*192 + h*32 + (mt&1)*16 + lg*4;
      float b0 = qb2[cb], b1 = qb2[cb+1], b2 = qb2[cb+2], b3 = qb2[cb+3];
      #pragma unroll
      for (int nt = 0; nt < 4; nt++){
        f32x4 a = acc[mt][nt];
        uint2v pk = { pk2(a[0]+b0, a[1]+b1), pk2(a[2]+b2, a[3]+b3) };
        if (mt < 2) q16[mt][nt] = pk; else k16[mt-2][nt] = pk;
      }
    }
  }
  { // ---- v via normal GEMM: D[l][c_out], lane: col=d=lj, j in regs
    f32x4 acc[4][2];
    #pragma unroll
    for (int mt = 0; mt < 4; mt++){ acc[mt][0] = (f32x4){0.f,0.f,0.f,0.f}; acc[mt][1] = (f32x4){0.f,0.f,0.f,0.f}; }
    #pragma unroll
    for (int ks = 0; ks < 6; ks++){
      short8 xf[4];
      #pragma unroll
      for (int mt = 0; mt < 4; mt++)
        xf[mt] = *(const short8*)((const char*)xa + (mt*16+lj)*384 + ((ks*64 + lg*16) ^ swz));
      #pragma unroll
      for (int nt = 0; nt < 2; nt++){
        short8 wb = *(const short8*)(qkvwt + (size_t)(384 + h*32 + nt*16 + lj)*192 + ks*32 + lg*8);
        #pragma unroll
        for (int mt = 0; mt < 4; mt++)
          acc[mt][nt] = __builtin_amdgcn_mfma_f32_16x16x32_bf16(xf[mt], wb, acc[mt][nt], 0, 0, 0);
      }
    }
    float vb0 = qb2[384 + h*32 + lj], vb1 = qb2[384 + h*32 + 16 + lj];
    #pragma unroll
    for (int mt = 0; mt < 4; mt++){
      f32x4 a0 = acc[mt][0], a1 = acc[mt][1];
      v16[0][mt] = (uint2v){ pk2(a0[0]+vb0, a0[1]+vb0), pk2(a0[2]+vb0, a0[3]+vb0) };
      v16[1][mt] = (uint2v){ pk2(a1[0]+vb1, a1[1]+vb1), pk2(a1[2]+vb1, a1[3]+vb1) };
    }
  }
  { // ---- attention, all-register: S^T = K·Q^T, softmax over j, O^T = V^T·P^T
    f32x4 st[4][4];  // [jt][it]: lane col=i=it*16+lj, regs j=jt*16+lg*4+e
    #pragma unroll
    for (int jt = 0; jt < 4; jt++)
      #pragma unroll
      for (int it = 0; it < 4; it++)
        st[jt][it] = __builtin_amdgcn_mfma_f32_16x16x32_bf16(
            cat(k16[0][jt], k16[1][jt]), cat(q16[0][it], q16[1][it]),
            (f32x4){0.f,0.f,0.f,0.f}, 0, 0, 0);
    const f32x4* cb = cmb2 + (size_t)(cc*6 + h)*16*64;
    #pragma unroll
    for (int jt = 0; jt < 4; jt++)
      #pragma unroll
      for (int it = 0; it < 4; it++)
        st[jt][it] += cb[(jt*4 + lg)*64 + it*16 + lj];

    uint2v p16[4][4];
    #pragma unroll
    for (int it = 0; it < 4; it++){
      float m = -3.0e38f;
      #pragma unroll
      for (int jt = 0; jt < 4; jt++)
        #pragma unroll
        for (int e = 0; e < 4; e++) m = fmaxf(m, st[jt][it][e]);
      m = fmaxf(m, __shfl_xor(m, 16)); m = fmaxf(m, __shfl_xor(m, 32));
      float s = 0.f;
      #pragma unroll
      for (int jt = 0; jt < 4; jt++)
        #pragma unroll
        for (int e = 0; e < 4; e++){
          float p = __expf(st[jt][it][e] - m);
          st[jt][it][e] = p; s += p;
        }
      s += __shfl_xor(s, 16); s += __shfl_xor(s, 32);
      float inv = 1.0f / s;
      #pragma unroll
      for (int jt = 0; jt < 4; jt++)
        p16[jt][it] = (uint2v){ pk2(st[jt][it][0]*inv, st[jt][it][1]*inv),
                                pk2(st[jt][it][2]*inv, st[jt][it][3]*inv) };
    }
    #pragma unroll
    for (int dt = 0; dt < 2; dt++)
      #pragma unroll
      for (int it = 0; it < 4; it++){
        f32x4 o = __builtin_amdgcn_mfma_f32_16x16x32_bf16(
            cat(v16[dt][0], v16[dt][1]), cat(p16[0][it], p16[1][it]),
            (f32x4){0.f,0.f,0.f,0.f}, 0, 0, 0);
        o = __builtin_amdgcn_mfma_f32_16x16x32_bf16(
            cat(v16[dt][2], v16[dt][3]), cat(p16[2][it], p16[3][it]), o, 0, 0, 0);
        uint2v w = { pk2(o[0], o[1]), pk2(o[2], o[3]) };
        *(uint2v*)((char*)xo + (it*16+lj)*400 + (h*32 + dt*16 + lg*4)*2) = w;
      }
  }
  __syncthreads();
  { // ---- proj: D[l][c_out] = xo @ proj_w, scatter with roll(+3,+3)
    f32x4 acc[4][2];
    #pragma unroll
    for (int mt = 0; mt < 4; mt++){ acc[mt][0] = (f32x4){0.f,0.f,0.f,0.f}; acc[mt][1] = (f32x4){0.f,0.f,0.f,0.f}; }
    #pragma unroll
    for (int ks = 0; ks < 6; ks++){
      short8 xf[4];
      #pragma unroll
      for (int mt = 0; mt < 4; mt++)
        xf[mt] = *(const short8*)((const char*)xo + (mt*16+lj)*400 + ks*64 + lg*16);
      #pragma unroll
      for (int nt = 0; nt < 2; nt++){
        short8 pw = *(const short8*)(pwt + (size_t)(h*32 + nt*16 + lj)*192 + ks*32 + lg*8);
        #pragma unroll
        for (int mt = 0; mt < 4; mt++)
          acc[mt][nt] = __builtin_amdgcn_mfma_f32_16x16x32_bf16(xf[mt], pw, acc[mt][nt], 0, 0, 0);
      }
    }
    float pb0 = proj_b[h*32 + lj], pb1 = proj_b[h*32 + 16 + lj];
    #pragma unroll
    for (int mt = 0; mt < 4; mt++)
      #pragma unroll
      for (int e = 0; e < 4; e++){
        int l = mt*16 + lg*4 + e;
        if (l < 49){
          int i = l/7, jx = l%7;
          int oh = wh*7 + i + 3; if (oh >= 56) oh -= 56;
          int ow = ww*7 + jx + 3; if (ow >= 56) ow -= 56;
          size_t base = (((size_t)b*56 + oh)*56 + ow)*192 + h*32;
          out[base + lj]      = acc[mt][0][e] + pb0;
          out[base + 16 + lj] = acc[mt][1][e] + pb1;
        }
      }
  }
}

// ------------------------------------------------------------------ launch -
extern "C" void kernel_launch(void* const* d_in, const int* in_sizes, int n_in,
                              void* d_out, int out_size, void* d_ws, size_t ws_size,
                              hipStream_t stream){
  const float* x         = (const float*)d_in[0];
  const float* qkv_w     = (const float*)d_in[1];
  const float* qkv_b     = (const float*)d_in[2];
  const float* proj_w    = (const float*)d_in[3];
  const float* proj_b    = (const float*)d_in[4];
  const float* rel_table = (const float*)d_in[5];

  if (ws_size < WS_NEED) return;

  char* ws = (char*)d_ws;
  ushort* qkvwt = (ushort*)(ws + OFF_QKVWT);
  ushort* pwt   = (ushort*)(ws + OFF_PWT);
  float*  qb2   = (float*) (ws + OFF_QB);
  float*  cmb2  = (float*) (ws + OFF_CMB2);
  float* out = (float*)d_out;

  k_setup<<<dim3(963), dim3(256), 0, stream>>>(qkv_w, qkv_b, proj_w, rel_table, qkvwt, pwt, qb2, cmb2);
  k_fused<<<dim3(4096), dim3(384), 0, stream>>>(x, qkvwt, qb2, pwt, proj_b, (const f32x4*)cmb2, out);
}